// Round 7
// baseline (334.844 us; speedup 1.0000x reference)
//
#include <hip/hip_runtime.h>
#include <math.h>

typedef unsigned short u16;
typedef unsigned int   u32;

using f32x4  = __attribute__((ext_vector_type(4))) float;
using s16x8  = __attribute__((ext_vector_type(8))) short;
using u16x8  = __attribute__((ext_vector_type(8))) unsigned short;

// ---------- helpers ----------
__device__ __forceinline__ u16 f2b(float f) {           // fp32 -> bf16 RNE
    u32 u = __float_as_uint(f);
    u += 0x7FFFu + ((u >> 16) & 1u);
    return (u16)(u >> 16);
}
__device__ __forceinline__ float b2f(u16 u) { return __uint_as_float(((u32)u) << 16); }

// window-order row R -> natural token row (b*256 + i*16 + j)
__device__ __forceinline__ int natrow(int R) {
    int b = R >> 8, r8 = R & 255, w = r8 >> 2, t = r8 & 3;
    return (b << 8) + ((((w >> 3) << 1) + (t >> 1)) << 4) + ((w & 7) << 1) + (t & 1);
}

__device__ __forceinline__ void gll16(const void* g, void* l) {
    __builtin_amdgcn_global_load_lds(
        (const __attribute__((address_space(1))) void*)g,
        (__attribute__((address_space(3))) void*)l, 16, 0, 0);
}

// ---------- weight repack: [R][C] f32 -> [C][R] bf16 ----------
__device__ __forceinline__ void transpose_body(
    const float* __restrict__ in, u16* __restrict__ out, int R, int C)
{
    __shared__ float tile[32][33];
    const int tx = threadIdx.x, ty = threadIdx.y;
    const int c  = blockIdx.x * 32 + tx;
    const int r0 = blockIdx.y * 32;
#pragma unroll
    for (int i = 0; i < 32; i += 8) tile[ty + i][tx] = in[(size_t)(r0 + ty + i) * C + c];
    __syncthreads();
    const int orow0 = blockIdx.x * 32;
    const int ocol  = r0 + tx;
#pragma unroll
    for (int i = 0; i < 32; i += 8)
        out[(size_t)(orow0 + ty + i) * R + ocol] = f2b(tile[tx][ty + i]);
}

// z in [0,48): Wq heads 0-15, Wk 16-31, Wv 32-47; each head [1024][64] -> [64][1024]
__global__ __launch_bounds__(256) void transpose_qkv(
    const float* __restrict__ Wq, const float* __restrict__ Wk,
    const float* __restrict__ Wv, u16* __restrict__ out)
{
    const int z = blockIdx.z;
    const float* in = (z < 16 ? Wq : z < 32 ? Wk : Wv) + (size_t)(z & 15) * 65536;
    transpose_body(in, out + (size_t)z * 65536, 1024, 64);
}

// z in [0,3): Wp, W1, W2; [1024][1024] -> transposed, outputs contiguous
__global__ __launch_bounds__(256) void transpose_pw(
    const float* __restrict__ Wp, const float* __restrict__ W1,
    const float* __restrict__ W2, u16* __restrict__ out)
{
    const int z = blockIdx.z;
    const float* in = z == 0 ? Wp : z == 1 ? W1 : W2;
    transpose_body(in, out + (size_t)z * 1048576, 1024, 1024);
}

// ---------- LayerNorm; MAP = window-gather rows, BIN = bf16 input ----------
template<int MAP, int BIN>
__global__ __launch_bounds__(256) void ln_kernel(
    const void* __restrict__ X, const float* __restrict__ g, const float* __restrict__ bta,
    u16* __restrict__ outB)
{
    const int R   = blockIdx.x;
    const int src = MAP ? natrow(R) : R;
    float x0, x1, x2, x3;
    if (BIN) {
        const ushort4 r = ((const ushort4*)((const u16*)X + (size_t)src * 1024))[threadIdx.x];
        x0 = b2f(r.x); x1 = b2f(r.y); x2 = b2f(r.z); x3 = b2f(r.w);
    } else {
        const float4 r = ((const float4*)((const float*)X + (size_t)src * 1024))[threadIdx.x];
        x0 = r.x; x1 = r.y; x2 = r.z; x3 = r.w;
    }
    float s  = x0 + x1 + x2 + x3;
    float s2 = x0 * x0 + x1 * x1 + x2 * x2 + x3 * x3;
#pragma unroll
    for (int o = 32; o; o >>= 1) { s += __shfl_xor(s, o); s2 += __shfl_xor(s2, o); }
    __shared__ float red[8];
    const int w = threadIdx.x >> 6, l = threadIdx.x & 63;
    if (l == 0) { red[w] = s; red[w + 4] = s2; }
    __syncthreads();
    s  = red[0] + red[1] + red[2] + red[3];
    s2 = red[4] + red[5] + red[6] + red[7];
    const float mean = s * (1.f / 1024.f);
    const float var  = s2 * (1.f / 1024.f) - mean * mean;
    const float rinv = rsqrtf(var + 1e-5f);
    const float4 gv = ((const float4*)g)[threadIdx.x];
    const float4 bv = ((const float4*)bta)[threadIdx.x];
    ((ushort4*)(outB + (size_t)R * 1024))[threadIdx.x] = make_ushort4(
        f2b((x0 - mean) * rinv * gv.x + bv.x), f2b((x1 - mean) * rinv * gv.y + bv.y),
        f2b((x2 - mean) * rinv * gv.z + bv.z), f2b((x3 - mean) * rinv * gv.w + bv.w));
}

// ---------- 128x256 4-wave GEMM, BK=32, row-pair swizzle, 2 blocks/CU ----------
// C[M][N] = A[M][K](bf16, row stride LDA) @ Bt[N][K](bf16)^T
// MODE 0: bf16            MODE 2: gelu(+bias) -> bf16
// MODE 3: +bias + bf16 resid -> f32 at natrow     MODE 5: +bias + bf16 resid -> bf16
//
// Wave tile 128x64 (grid 1x4) = optimal LDS-read/flop under 256-VGPR/wave.
// LDS 48KB: buf d at d*24576: A [64 rowpairs][128B] at 0, B [128 rp][128B] at 8192.
// BK=32 -> 64B logical rows; row-PAIR layout packs 2 rows per 128B line; swizzle
// slot ^= (rp&7) spreads 16 lanes over 8 slot-groups exactly 2x (free, m136).
// Stage (global_load_lds, linear dest) sources pre-permuted by same involution:
// chunk c: rp=c>>3, sl=(c&7)^(rp&7), row=rp*2+(sl>>2), k8=sl&3.
// Per tile: 4 b-reads | SB | 4 a-reads | SB | 4 a-reads | SB | 6 gll stage |
// lgkmcnt(4) -> MFMA i0..3 | lgkmcnt(0) -> MFMA i4..7 | vmcnt(0)+barrier.
// 48KB x 2 blocks/CU = 96KB; two blocks' phases interleave across barriers.
template<int MODE>
__global__ __launch_bounds__(256, 2) void gemm128(
    const u16* __restrict__ A, const u16* __restrict__ Bt,
    const float* __restrict__ bias, const void* __restrict__ resid,
    void* __restrict__ Out, int M, int N, int K, int LDA, int NB)
{
    extern __shared__ char lds[];
    const int NT = K >> 5;                       // BK=32, NT even
    const int nblk = gridDim.x;
    const int lb = (blockIdx.x & 7) * (nblk >> 3) + (blockIdx.x >> 3);
    const int mb = lb / NB, nb = lb - mb * NB;
    const int row0 = mb * 128, col0 = nb * 256;
    const int tid = threadIdx.x;
    const int w = tid >> 6, l = tid & 63;
    const int lr = l & 15, kg = l >> 4;
    // per-lane swizzled read base: row-pair rp=lr>>1, in-pair slot = (lr&1)*4 + kg
    const int laneoff = (lr >> 1) * 128 +
        ((((lr & 1) << 6) | (kg << 4)) ^ (((lr >> 1) & 7) << 4));
    const char* vA = lds + laneoff;
    const char* vB = lds + 8192 + w * 4096 + laneoff;

    // stage source pointers (pre-permuted)
    const u16* sA[2]; const u16* sB[4];
#pragma unroll
    for (int j = 0; j < 2; ++j) {
        const int c = j * 256 + tid, rp = c >> 3, sl = (c & 7) ^ (rp & 7);
        sA[j] = A + (size_t)(row0 + rp * 2 + (sl >> 2)) * LDA + (sl & 3) * 8;
    }
#pragma unroll
    for (int j = 0; j < 4; ++j) {
        const int c = j * 256 + tid, rp = c >> 3, sl = (c & 7) ^ (rp & 7);
        sB[j] = Bt + (size_t)(col0 + rp * 2 + (sl >> 2)) * K + (sl & 3) * 8;
    }

    f32x4 acc[8][4] = {};
    s16x8 a[8], b[4];

#define SB __builtin_amdgcn_sched_barrier(0)
#define STAGE(dd, ts) do { \
    gll16(sA[0] + (ts) * 32, lds + (dd) * 24576 +         w * 1024); \
    gll16(sA[1] + (ts) * 32, lds + (dd) * 24576 +  4096 + w * 1024); \
    gll16(sB[0] + (ts) * 32, lds + (dd) * 24576 +  8192 + w * 1024); \
    gll16(sB[1] + (ts) * 32, lds + (dd) * 24576 + 12288 + w * 1024); \
    gll16(sB[2] + (ts) * 32, lds + (dd) * 24576 + 16384 + w * 1024); \
    gll16(sB[3] + (ts) * 32, lds + (dd) * 24576 + 20480 + w * 1024); \
} while (0)
#define G4(i) do { \
    acc[i][0] = __builtin_amdgcn_mfma_f32_16x16x32_bf16(a[i], b[0], acc[i][0], 0, 0, 0); \
    acc[i][1] = __builtin_amdgcn_mfma_f32_16x16x32_bf16(a[i], b[1], acc[i][1], 0, 0, 0); \
    acc[i][2] = __builtin_amdgcn_mfma_f32_16x16x32_bf16(a[i], b[2], acc[i][2], 0, 0, 0); \
    acc[i][3] = __builtin_amdgcn_mfma_f32_16x16x32_bf16(a[i], b[3], acc[i][3], 0, 0, 0); \
} while (0)
#define TILE(d, t) do { \
    b[0] = *(const s16x8*)(vB + (d) * 24576 +    0); \
    b[1] = *(const s16x8*)(vB + (d) * 24576 + 1024); \
    b[2] = *(const s16x8*)(vB + (d) * 24576 + 2048); \
    b[3] = *(const s16x8*)(vB + (d) * 24576 + 3072); \
    SB; \
    a[0] = *(const s16x8*)(vA + (d) * 24576 +    0); \
    a[1] = *(const s16x8*)(vA + (d) * 24576 + 1024); \
    a[2] = *(const s16x8*)(vA + (d) * 24576 + 2048); \
    a[3] = *(const s16x8*)(vA + (d) * 24576 + 3072); \
    SB; \
    a[4] = *(const s16x8*)(vA + (d) * 24576 + 4096); \
    a[5] = *(const s16x8*)(vA + (d) * 24576 + 5120); \
    a[6] = *(const s16x8*)(vA + (d) * 24576 + 6144); \
    a[7] = *(const s16x8*)(vA + (d) * 24576 + 7168); \
    SB; \
    if ((t) + 1 < NT) STAGE((d) ^ 1, (t) + 1); \
    SB; \
    __builtin_amdgcn_s_setprio(1); \
    asm volatile("s_waitcnt lgkmcnt(4)" ::: "memory"); SB; \
    G4(0); G4(1); G4(2); G4(3); \
    asm volatile("s_waitcnt lgkmcnt(0)" ::: "memory"); SB; \
    G4(4); G4(5); G4(6); G4(7); \
    __builtin_amdgcn_s_setprio(0); SB; \
    if ((t) + 1 < NT) { \
        asm volatile("s_waitcnt vmcnt(0)" ::: "memory"); \
        __builtin_amdgcn_s_barrier(); SB; \
    } \
} while (0)

    // prologue: stage tile 0 into buf 0
    STAGE(0, 0);
    asm volatile("s_waitcnt vmcnt(0)" ::: "memory");
    __builtin_amdgcn_s_barrier();

    for (int t = 0; t < NT; t += 2) {
        TILE(0, t);
        TILE(1, t + 1);
    }
#undef SB
#undef STAGE
#undef G4
#undef TILE

    // epilogue: rows row0 + i*16 + kg*4 + j; cols col0 + w*64 + n*16 + lr
#pragma unroll
    for (int i = 0; i < 8; ++i) {
        const int grb = row0 + i * 16 + kg * 4;
#pragma unroll
        for (int n = 0; n < 4; ++n) {
            const int gc = col0 + w * 64 + n * 16 + lr;
#pragma unroll
            for (int j = 0; j < 4; ++j) {
                const int gr = grb + j;
                const float v = acc[i][n][j];
                if (MODE == 0) {
                    ((u16*)Out)[(size_t)gr * N + gc] = f2b(v);
                } else if (MODE == 2) {
                    const float tt = v + bias[gc];
                    ((u16*)Out)[(size_t)gr * N + gc] = f2b(0.5f * tt * (1.f + erff(tt * 0.70710678118f)));
                } else if (MODE == 3) {
                    ((float*)Out)[(size_t)natrow(gr) * N + gc] =
                        v + bias[gc] + b2f(((const u16*)resid)[(size_t)gr * N + gc]);
                } else {
                    ((u16*)Out)[(size_t)gr * N + gc] =
                        f2b(v + bias[gc] + b2f(((const u16*)resid)[(size_t)gr * N + gc]));
                }
            }
        }
    }
}

// ---------- tiny windowed attention, vectorized short8, in-place into q cols ----------
// one wave per window; lane l, chunk c covers cols c*512 + l*8 (head = c*8 + (l>>3))
__global__ __launch_bounds__(256) void attn_kernel(u16* __restrict__ QKV)
{
    const int w = threadIdx.x >> 6, l = threadIdx.x & 63;
    const int n = blockIdx.x * 4 + w;             // 4096 windows
    u16* base = QKV + (size_t)n * 4 * 3072;
    const float scale = 0.03125f;                 // C^-0.5 = 1/32 (d_model!)
#pragma unroll
    for (int c = 0; c < 2; ++c) {
        const int col = c * 512 + l * 8;
        u16x8 qr[4], kr[4], vr[4];
#pragma unroll
        for (int t = 0; t < 4; ++t) {
            qr[t] = *(const u16x8*)(base + t * 3072 + col);
            kr[t] = *(const u16x8*)(base + t * 3072 + 1024 + col);
            vr[t] = *(const u16x8*)(base + t * 3072 + 2048 + col);
        }
        float qf[4][8], kf[4][8];
#pragma unroll
        for (int t = 0; t < 4; ++t)
#pragma unroll
            for (int j = 0; j < 8; ++j) { qf[t][j] = b2f(qr[t][j]); kf[t][j] = b2f(kr[t][j]); }
        float s[4][4];
#pragma unroll
        for (int t = 0; t < 4; ++t)
#pragma unroll
            for (int u = 0; u < 4; ++u) {
                float p = qf[t][0] * kf[u][0];
#pragma unroll
                for (int j = 1; j < 8; ++j) p += qf[t][j] * kf[u][j];
                p += __shfl_xor(p, 1); p += __shfl_xor(p, 2); p += __shfl_xor(p, 4);
                s[t][u] = p * scale;              // per-head dot (8-lane group)
            }
#pragma unroll
        for (int t = 0; t < 4; ++t) {
            const float m = fmaxf(fmaxf(s[t][0], s[t][1]), fmaxf(s[t][2], s[t][3]));
            const float e0 = expf(s[t][0] - m), e1 = expf(s[t][1] - m);
            const float e2 = expf(s[t][2] - m), e3 = expf(s[t][3] - m);
            const float inv = 1.f / (e0 + e1 + e2 + e3);
            u16x8 o;
#pragma unroll
            for (int j = 0; j < 8; ++j)
                o[j] = f2b((e0 * b2f(vr[0][j]) + e1 * b2f(vr[1][j]) +
                            e2 * b2f(vr[2][j]) + e3 * b2f(vr[3][j])) * inv);
            *(u16x8*)(base + t * 3072 + col) = o; // overwrite own q slot (wave-private)
        }
    }
}

// ---------- launch ----------
extern "C" void kernel_launch(void* const* d_in, const int* in_sizes, int n_in,
                              void* d_out, int out_size, void* d_ws, size_t ws_size,
                              hipStream_t stream)
{
    const float* x    = (const float*)d_in[0];
    const float* ln1g = (const float*)d_in[1];
    const float* ln1b = (const float*)d_in[2];
    const float* Wq   = (const float*)d_in[3];
    const float* Wk   = (const float*)d_in[4];
    const float* Wv   = (const float*)d_in[5];
    const float* Wp   = (const float*)d_in[6];
    const float* bp   = (const float*)d_in[7];
    const float* ln2g = (const float*)d_in[8];
    const float* ln2b = (const float*)d_in[9];
    const float* W1   = (const float*)d_in[10];
    const float* b1   = (const float*)d_in[11];
    const float* W2   = (const float*)d_in[12];
    const float* b2   = (const float*)d_in[13];
    float* out = (float*)d_out;

    char* ws = (char*)d_ws;
    const size_t MB = 1024 * 1024;
    u16* xr_b  = (u16*)ws;                        // 32MB: xr bf16 (residual spine)
    u16* xw_b  = (u16*)(ws + 32 * MB);            // 32MB: ln1(x) windowed bf16
    u16* qkv   = (u16*)(ws + 64 * MB);            // 96MB: q|k|v; attn in-place; dead after proj
    u16* h1b   = (u16*)(ws + 64 * MB);            // 32MB: reuse of qkv region after proj
    u16* ln2bf = (u16*)(ws + 160 * MB);           // 32MB
    u16* WqkvT = (u16*)(ws + 192 * MB);           // 6MB [3072][1024]
    u16* WpT   = (u16*)(ws + 198 * MB);           // 3 x 2MB contiguous
    u16* W1T   = WpT + (1u << 20);
    u16* W2T   = W1T + (1u << 20);

    hipFuncSetAttribute((const void*)gemm128<0>, hipFuncAttributeMaxDynamicSharedMemorySize, 49152);
    hipFuncSetAttribute((const void*)gemm128<2>, hipFuncAttributeMaxDynamicSharedMemorySize, 49152);
    hipFuncSetAttribute((const void*)gemm128<3>, hipFuncAttributeMaxDynamicSharedMemorySize, 49152);
    hipFuncSetAttribute((const void*)gemm128<5>, hipFuncAttributeMaxDynamicSharedMemorySize, 49152);

    const int M = 16384, K = 1024;
    dim3 tpb(32, 8);
    transpose_qkv<<<dim3(2, 32, 48), tpb, 0, stream>>>(Wq, Wk, Wv, WqkvT);
    transpose_pw <<<dim3(32, 32, 3), tpb, 0, stream>>>(Wp, W1, W2, WpT);

    ln_kernel<1, 0><<<16384, 256, 0, stream>>>(x, ln1g, ln1b, xw_b);

    // qkv = xw @ [Wq|Wk|Wv]   (N=3072): 128x12 = 1536 blocks, 6/CU rounds of 2
    gemm128<0><<<1536, 256, 49152, stream>>>(xw_b, WqkvT, nullptr, nullptr, qkv, M, 3072, K, K, 12);

    attn_kernel<<<1024, 256, 0, stream>>>(qkv);    // att overwrites q columns

    // xr = att @ Wp + bp + xw  -> bf16 spine   (128x4 = 512 blocks = exactly 2/CU)
    gemm128<5><<<512, 256, 49152, stream>>>(qkv, WpT, bp, xw_b, xr_b, M, 1024, K, 3072, 4);

    ln_kernel<0, 1><<<16384, 256, 0, stream>>>(xr_b, ln2g, ln2b, ln2bf);

    // h1 = gelu(ln2 @ W1 + b1)   (qkv region is dead now -> h1b)
    gemm128<2><<<512, 256, 49152, stream>>>(ln2bf, W1T, b1, nullptr, h1b, M, 1024, K, K, 4);

    // out[natrow] = h1 @ W2 + b2 + xr
    gemm128<3><<<512, 256, 49152, stream>>>(h1b, W2T, b2, xr_b, out, M, 1024, K, K, 4);
}

// Round 8
// 311.032 us; speedup vs baseline: 1.0766x; 1.0766x over previous
//
#include <hip/hip_runtime.h>
#include <math.h>

typedef unsigned short u16;
typedef unsigned int   u32;

using f32x4  = __attribute__((ext_vector_type(4))) float;
using s16x8  = __attribute__((ext_vector_type(8))) short;
using u16x8  = __attribute__((ext_vector_type(8))) unsigned short;

// ---------- helpers ----------
__device__ __forceinline__ u16 f2b(float f) {           // fp32 -> bf16 RNE
    u32 u = __float_as_uint(f);
    u += 0x7FFFu + ((u >> 16) & 1u);
    return (u16)(u >> 16);
}
__device__ __forceinline__ float b2f(u16 u) { return __uint_as_float(((u32)u) << 16); }

// window-order row R -> natural token row (b*256 + i*16 + j)
__device__ __forceinline__ int natrow(int R) {
    int b = R >> 8, r8 = R & 255, w = r8 >> 2, t = r8 & 3;
    return (b << 8) + ((((w >> 3) << 1) + (t >> 1)) << 4) + ((w & 7) << 1) + (t & 1);
}

__device__ __forceinline__ void gll16(const void* g, void* l) {
    __builtin_amdgcn_global_load_lds(
        (const __attribute__((address_space(1))) void*)g,
        (__attribute__((address_space(3))) void*)l, 16, 0, 0);
}

// ---------- weight repack: [R][C] f32 -> [C][R] bf16 ----------
__device__ __forceinline__ void transpose_body(
    const float* __restrict__ in, u16* __restrict__ out, int R, int C)
{
    __shared__ float tile[32][33];
    const int tx = threadIdx.x, ty = threadIdx.y;
    const int c  = blockIdx.x * 32 + tx;
    const int r0 = blockIdx.y * 32;
#pragma unroll
    for (int i = 0; i < 32; i += 8) tile[ty + i][tx] = in[(size_t)(r0 + ty + i) * C + c];
    __syncthreads();
    const int orow0 = blockIdx.x * 32;
    const int ocol  = r0 + tx;
#pragma unroll
    for (int i = 0; i < 32; i += 8)
        out[(size_t)(orow0 + ty + i) * R + ocol] = f2b(tile[tx][ty + i]);
}

// z in [0,48): Wq heads 0-15, Wk 16-31, Wv 32-47; each head [1024][64] -> [64][1024]
__global__ __launch_bounds__(256) void transpose_qkv(
    const float* __restrict__ Wq, const float* __restrict__ Wk,
    const float* __restrict__ Wv, u16* __restrict__ out)
{
    const int z = blockIdx.z;
    const float* in = (z < 16 ? Wq : z < 32 ? Wk : Wv) + (size_t)(z & 15) * 65536;
    transpose_body(in, out + (size_t)z * 65536, 1024, 64);
}

// z in [0,3): Wp, W1, W2; [1024][1024] -> transposed, outputs contiguous
__global__ __launch_bounds__(256) void transpose_pw(
    const float* __restrict__ Wp, const float* __restrict__ W1,
    const float* __restrict__ W2, u16* __restrict__ out)
{
    const int z = blockIdx.z;
    const float* in = z == 0 ? Wp : z == 1 ? W1 : W2;
    transpose_body(in, out + (size_t)z * 1048576, 1024, 1024);
}

// ---------- LayerNorm; MAP = window-gather rows, BIN = bf16 input ----------
template<int MAP, int BIN>
__global__ __launch_bounds__(256) void ln_kernel(
    const void* __restrict__ X, const float* __restrict__ g, const float* __restrict__ bta,
    u16* __restrict__ outB)
{
    const int R   = blockIdx.x;
    const int src = MAP ? natrow(R) : R;
    float x0, x1, x2, x3;
    if (BIN) {
        const ushort4 r = ((const ushort4*)((const u16*)X + (size_t)src * 1024))[threadIdx.x];
        x0 = b2f(r.x); x1 = b2f(r.y); x2 = b2f(r.z); x3 = b2f(r.w);
    } else {
        const float4 r = ((const float4*)((const float*)X + (size_t)src * 1024))[threadIdx.x];
        x0 = r.x; x1 = r.y; x2 = r.z; x3 = r.w;
    }
    float s  = x0 + x1 + x2 + x3;
    float s2 = x0 * x0 + x1 * x1 + x2 * x2 + x3 * x3;
#pragma unroll
    for (int o = 32; o; o >>= 1) { s += __shfl_xor(s, o); s2 += __shfl_xor(s2, o); }
    __shared__ float red[8];
    const int w = threadIdx.x >> 6, l = threadIdx.x & 63;
    if (l == 0) { red[w] = s; red[w + 4] = s2; }
    __syncthreads();
    s  = red[0] + red[1] + red[2] + red[3];
    s2 = red[4] + red[5] + red[6] + red[7];
    const float mean = s * (1.f / 1024.f);
    const float var  = s2 * (1.f / 1024.f) - mean * mean;
    const float rinv = rsqrtf(var + 1e-5f);
    const float4 gv = ((const float4*)g)[threadIdx.x];
    const float4 bv = ((const float4*)bta)[threadIdx.x];
    ((ushort4*)(outB + (size_t)R * 1024))[threadIdx.x] = make_ushort4(
        f2b((x0 - mean) * rinv * gv.x + bv.x), f2b((x1 - mean) * rinv * gv.y + bv.y),
        f2b((x2 - mean) * rinv * gv.z + bv.z), f2b((x3 - mean) * rinv * gv.w + bv.w));
}

// ---------- 256x256 8-wave GEMM, BK=64, m201-style counted-vmcnt phases ----------
// C[M][N] = A[M][K](bf16, row stride LDA) @ Bt[N][K](bf16)^T
// MODE 0: bf16            MODE 2: gelu(+bias) -> bf16
// MODE 3: +bias + bf16 resid -> f32 at natrow     MODE 5: +bias + bf16 resid -> bf16
//
// LDS (128KB): A [d][half][128 rows][128B] at d*32K+half*16K; B at +64KB.
// Swizzle (3-bit): phys_byte = lin_byte ^ ((row&7)<<4); gll sources pre-permuted
// by same involution in 16B chunks: q = p ^ ((p>>3)&7).  (conflict-free, r3 PMC)
//
// Phase schedule (per K-tile, snake quadrants (0,0)(1,0)(1,1)(0,1)):
//  ph0: vmcnt(4) barrier | ds_read a0,b0 (12) | stage A0(t+1) | lgkm0 | 16 MFMA
//  ph1: vmcnt(4) barrier | ds_read a1     (8) | stage B0(t+1) | lgkm0 | 16 MFMA
//  ph2: vmcnt(4) barrier | ds_read b1     (4) | stage A1(t+1) | lgkm0 | 16 MFMA
//  ph3:                  |                    | stage B1(t+1) |       | 16 MFMA
// Per-wave retire accounting (2 loads/half-tile): ph0 sees 8 outstanding,
// vmcnt(4) retires exactly A0,B0 of t; ph1 sees 6, retires A1; ph2 sees 6,
// retires B1. Every awaited load is >=3 phases (~2000cyc) old -> HBM covered;
// counter NEVER drains to 0 in the main loop. Last tile peeled: waits 4/2/0.
// WAR safety: tile-t ds_reads all drain at ph2's lgkm0; stages into tile-t's
// buffer first occur after (t+1).ph0's barrier, >=1 barrier later.
template<int MODE>
__global__ __launch_bounds__(512, 2) void gemm256(
    const u16* __restrict__ A, const u16* __restrict__ Bt,
    const float* __restrict__ bias, const void* __restrict__ resid,
    void* __restrict__ Out, int M, int N, int K, int LDA, int NB)
{
    extern __shared__ char lds[];
    const int NT = K >> 6;
    const int nblk = gridDim.x;
    const int lb = (blockIdx.x & 7) * (nblk >> 3) + (blockIdx.x >> 3);
    const int mb = lb / NB, nb = lb - mb * NB;
    const int row0 = mb * 256, col0 = nb * 256;
    const int tid = threadIdx.x;
    const int w = tid >> 6, l = tid & 63;
    const int wr = w >> 2, wc = w & 3;
    const int lr = l & 15, kg = l >> 4;
    const int xs = (lr & 7) << 4;
    const int koff[2] = { (kg * 16) ^ xs, (64 + kg * 16) ^ xs };
    const int abase_l = wr * 8192 + lr * 128;
    const int bbase_l = wc * 4096 + lr * 128;

    f32x4 acc[2][2][4][2] = {};                   // [qm][qn][i][n]
    s16x8 a0[4][2], a1[4][2], b0[2][2], b1[2][2];

    auto stage = [&](int ts, int item) {          // item: 0=A0 1=B0 2=A1 3=B1
        if (ts >= NT) return;
        const int d = ts & 1;
        const int isB = item & 1, h = item >> 1;
        char* lbase = lds + (isB ? 65536 : 0) + d * 32768 + h * 16384;
        const u16* gptr = isB ? Bt : A;
        const int ld = isB ? K : LDA;
        const int blk0 = (isB ? col0 : row0) + h * 128;
#pragma unroll
        for (int j = 0; j < 2; ++j) {
            const int p = j * 512 + tid;
            const int q = p ^ ((p >> 3) & 7);     // involution, row-preserving
            const int grow = blk0 + (q >> 3);
            const int gcol = ts * 64 + (q & 7) * 8;
            gll16(gptr + (size_t)grow * ld + gcol, lbase + (j * 8 + w) * 1024);
        }
    };

#define SB __builtin_amdgcn_sched_barrier(0)
#define LOAD_A(dst, qm) do { \
    _Pragma("unroll") for (int kk = 0; kk < 2; ++kk) \
    _Pragma("unroll") for (int i = 0; i < 4; ++i) \
        dst[i][kk] = *(const s16x8*)(Ab + (qm) * 16384 + abase_l + i * 2048 + koff[kk]); \
} while (0)
#define LOAD_B(dst, qn) do { \
    _Pragma("unroll") for (int kk = 0; kk < 2; ++kk) \
    _Pragma("unroll") for (int n = 0; n < 2; ++n) \
        dst[n][kk] = *(const s16x8*)(Bb + (qn) * 16384 + bbase_l + n * 2048 + koff[kk]); \
} while (0)
#define LGKM0 do { \
    asm volatile("s_waitcnt lgkmcnt(0)" ::: "memory"); SB; \
} while (0)
#define MFMA_Q(qm, qn, aa, bb) do { \
    __builtin_amdgcn_s_setprio(1); \
    _Pragma("unroll") for (int kk = 0; kk < 2; ++kk) \
    _Pragma("unroll") for (int i = 0; i < 4; ++i) \
    _Pragma("unroll") for (int n = 0; n < 2; ++n) \
        acc[qm][qn][i][n] = __builtin_amdgcn_mfma_f32_16x16x32_bf16( \
            aa[i][kk], bb[n][kk], acc[qm][qn][i][n], 0, 0, 0); \
    __builtin_amdgcn_s_setprio(0); SB; \
} while (0)
#define GATE(NSTR) do { \
    asm volatile("s_waitcnt vmcnt(" NSTR ")" ::: "memory"); \
    __builtin_amdgcn_s_barrier(); SB; \
} while (0)

    // prologue: stage tile 0's four half-tiles (8 loads in flight)
    stage(0, 0); stage(0, 1); stage(0, 2); stage(0, 3);

    for (int t = 0; t < NT - 1; ++t) {
        const char* Ab = lds + (t & 1) * 32768;
        const char* Bb = lds + 65536 + (t & 1) * 32768;
        // ph0
        GATE("4");
        LOAD_A(a0, 0); LOAD_B(b0, 0); SB;
        stage(t + 1, 0); SB;
        LGKM0;
        MFMA_Q(0, 0, a0, b0);
        // ph1
        GATE("4");
        LOAD_A(a1, 1); SB;
        stage(t + 1, 1); SB;
        LGKM0;
        MFMA_Q(1, 0, a1, b0);
        // ph2
        GATE("4");
        LOAD_B(b1, 1); SB;
        stage(t + 1, 2); SB;
        LGKM0;
        MFMA_Q(1, 1, a1, b1);
        // ph3 (no wait, no barrier, no reads)
        stage(t + 1, 3); SB;
        MFMA_Q(0, 1, a0, b1);
    }
    {   // last tile, peeled: no stages; waits 4 / 2 / 0
        const int t = NT - 1;
        const char* Ab = lds + (t & 1) * 32768;
        const char* Bb = lds + 65536 + (t & 1) * 32768;
        GATE("4");
        LOAD_A(a0, 0); LOAD_B(b0, 0); SB;
        LGKM0;
        MFMA_Q(0, 0, a0, b0);
        GATE("2");
        LOAD_A(a1, 1); SB;
        LGKM0;
        MFMA_Q(1, 0, a1, b0);
        GATE("0");
        LOAD_B(b1, 1); SB;
        LGKM0;
        MFMA_Q(1, 1, a1, b1);
        MFMA_Q(0, 1, a0, b1);
    }
#undef SB
#undef LOAD_A
#undef LOAD_B
#undef LGKM0
#undef MFMA_Q
#undef GATE

    // epilogue
#pragma unroll
    for (int qm = 0; qm < 2; ++qm)
#pragma unroll
    for (int i = 0; i < 4; ++i) {
        const int grb = row0 + qm * 128 + wr * 64 + i * 16 + kg * 4;
#pragma unroll
        for (int qn = 0; qn < 2; ++qn)
#pragma unroll
        for (int n = 0; n < 2; ++n) {
            const int gc = col0 + qn * 128 + wc * 32 + n * 16 + lr;
#pragma unroll
            for (int j = 0; j < 4; ++j) {
                const int gr = grb + j;
                const float v = acc[qm][qn][i][n][j];
                if (MODE == 0) {
                    ((u16*)Out)[(size_t)gr * N + gc] = f2b(v);
                } else if (MODE == 2) {
                    const float tt = v + bias[gc];
                    ((u16*)Out)[(size_t)gr * N + gc] = f2b(0.5f * tt * (1.f + erff(tt * 0.70710678118f)));
                } else if (MODE == 3) {
                    ((float*)Out)[(size_t)natrow(gr) * N + gc] =
                        v + bias[gc] + b2f(((const u16*)resid)[(size_t)gr * N + gc]);
                } else {
                    ((u16*)Out)[(size_t)gr * N + gc] =
                        f2b(v + bias[gc] + b2f(((const u16*)resid)[(size_t)gr * N + gc]));
                }
            }
        }
    }
}

// ---------- tiny windowed attention, vectorized short8, in-place into q cols ----------
// one wave per window; lane l, chunk c covers cols c*512 + l*8 (head = c*8 + (l>>3))
__global__ __launch_bounds__(256) void attn_kernel(u16* __restrict__ QKV)
{
    const int w = threadIdx.x >> 6, l = threadIdx.x & 63;
    const int n = blockIdx.x * 4 + w;             // 4096 windows
    u16* base = QKV + (size_t)n * 4 * 3072;
    const float scale = 0.03125f;                 // C^-0.5 = 1/32 (d_model!)
#pragma unroll
    for (int c = 0; c < 2; ++c) {
        const int col = c * 512 + l * 8;
        u16x8 qr[4], kr[4], vr[4];
#pragma unroll
        for (int t = 0; t < 4; ++t) {
            qr[t] = *(const u16x8*)(base + t * 3072 + col);
            kr[t] = *(const u16x8*)(base + t * 3072 + 1024 + col);
            vr[t] = *(const u16x8*)(base + t * 3072 + 2048 + col);
        }
        float qf[4][8], kf[4][8];
#pragma unroll
        for (int t = 0; t < 4; ++t)
#pragma unroll
            for (int j = 0; j < 8; ++j) { qf[t][j] = b2f(qr[t][j]); kf[t][j] = b2f(kr[t][j]); }
        float s[4][4];
#pragma unroll
        for (int t = 0; t < 4; ++t)
#pragma unroll
            for (int u = 0; u < 4; ++u) {
                float p = qf[t][0] * kf[u][0];
#pragma unroll
                for (int j = 1; j < 8; ++j) p += qf[t][j] * kf[u][j];
                p += __shfl_xor(p, 1); p += __shfl_xor(p, 2); p += __shfl_xor(p, 4);
                s[t][u] = p * scale;              // per-head dot (8-lane group)
            }
#pragma unroll
        for (int t = 0; t < 4; ++t) {
            const float m = fmaxf(fmaxf(s[t][0], s[t][1]), fmaxf(s[t][2], s[t][3]));
            const float e0 = expf(s[t][0] - m), e1 = expf(s[t][1] - m);
            const float e2 = expf(s[t][2] - m), e3 = expf(s[t][3] - m);
            const float inv = 1.f / (e0 + e1 + e2 + e3);
            u16x8 o;
#pragma unroll
            for (int j = 0; j < 8; ++j)
                o[j] = f2b((e0 * b2f(vr[0][j]) + e1 * b2f(vr[1][j]) +
                            e2 * b2f(vr[2][j]) + e3 * b2f(vr[3][j])) * inv);
            *(u16x8*)(base + t * 3072 + col) = o; // overwrite own q slot (wave-private)
        }
    }
}

// ---------- launch ----------
extern "C" void kernel_launch(void* const* d_in, const int* in_sizes, int n_in,
                              void* d_out, int out_size, void* d_ws, size_t ws_size,
                              hipStream_t stream)
{
    const float* x    = (const float*)d_in[0];
    const float* ln1g = (const float*)d_in[1];
    const float* ln1b = (const float*)d_in[2];
    const float* Wq   = (const float*)d_in[3];
    const float* Wk   = (const float*)d_in[4];
    const float* Wv   = (const float*)d_in[5];
    const float* Wp   = (const float*)d_in[6];
    const float* bp   = (const float*)d_in[7];
    const float* ln2g = (const float*)d_in[8];
    const float* ln2b = (const float*)d_in[9];
    const float* W1   = (const float*)d_in[10];
    const float* b1   = (const float*)d_in[11];
    const float* W2   = (const float*)d_in[12];
    const float* b2   = (const float*)d_in[13];
    float* out = (float*)d_out;

    char* ws = (char*)d_ws;
    const size_t MB = 1024 * 1024;
    u16* xr_b  = (u16*)ws;                        // 32MB: xr bf16 (residual spine)
    u16* xw_b  = (u16*)(ws + 32 * MB);            // 32MB: ln1(x) windowed bf16
    u16* qkv   = (u16*)(ws + 64 * MB);            // 96MB: q|k|v; attn in-place; dead after proj
    u16* h1b   = (u16*)(ws + 64 * MB);            // 32MB: reuse of qkv region after proj
    u16* ln2bf = (u16*)(ws + 160 * MB);           // 32MB
    u16* WqkvT = (u16*)(ws + 192 * MB);           // 6MB [3072][1024]
    u16* WpT   = (u16*)(ws + 198 * MB);           // 3 x 2MB contiguous
    u16* W1T   = WpT + (1u << 20);
    u16* W2T   = W1T + (1u << 20);

    hipFuncSetAttribute((const void*)gemm256<0>, hipFuncAttributeMaxDynamicSharedMemorySize, 131072);
    hipFuncSetAttribute((const void*)gemm256<2>, hipFuncAttributeMaxDynamicSharedMemorySize, 131072);
    hipFuncSetAttribute((const void*)gemm256<3>, hipFuncAttributeMaxDynamicSharedMemorySize, 131072);
    hipFuncSetAttribute((const void*)gemm256<5>, hipFuncAttributeMaxDynamicSharedMemorySize, 131072);

    const int M = 16384, K = 1024;
    dim3 tpb(32, 8);
    transpose_qkv<<<dim3(2, 32, 48), tpb, 0, stream>>>(Wq, Wk, Wv, WqkvT);
    transpose_pw <<<dim3(32, 32, 3), tpb, 0, stream>>>(Wp, W1, W2, WpT);

    ln_kernel<1, 0><<<16384, 256, 0, stream>>>(x, ln1g, ln1b, xw_b);

    // qkv = xw @ [Wq|Wk|Wv]   (N=3072)
    gemm256<0><<<768, 512, 131072, stream>>>(xw_b, WqkvT, nullptr, nullptr, qkv, M, 3072, K, K, 12);

    attn_kernel<<<1024, 256, 0, stream>>>(qkv);    // att overwrites q columns

    // xr = att @ Wp + bp + xw  -> bf16 spine
    gemm256<5><<<256, 512, 131072, stream>>>(qkv, WpT, bp, xw_b, xr_b, M, 1024, K, 3072, 4);

    ln_kernel<0, 1><<<16384, 256, 0, stream>>>(xr_b, ln2g, ln2b, ln2bf);

    // h1 = gelu(ln2 @ W1 + b1)
    gemm256<2><<<256, 512, 131072, stream>>>(ln2bf, W1T, b1, nullptr, h1b, M, 1024, K, K, 4);

    // out[natrow] = h1 @ W2 + b2 + xr
    gemm256<3><<<256, 512, 131072, stream>>>(h1b, W2T, b2, xr_b, out, M, 1024, K, K, 4);
}

// Round 9
// 310.174 us; speedup vs baseline: 1.0795x; 1.0028x over previous
//
#include <hip/hip_runtime.h>
#include <math.h>

typedef unsigned short u16;
typedef unsigned int   u32;

using f32x4  = __attribute__((ext_vector_type(4))) float;
using s16x8  = __attribute__((ext_vector_type(8))) short;
using u16x8  = __attribute__((ext_vector_type(8))) unsigned short;

// ---------- helpers ----------
__device__ __forceinline__ u16 f2b(float f) {           // fp32 -> bf16 RNE
    u32 u = __float_as_uint(f);
    u += 0x7FFFu + ((u >> 16) & 1u);
    return (u16)(u >> 16);
}
__device__ __forceinline__ float b2f(u16 u) { return __uint_as_float(((u32)u) << 16); }

// window-order row R -> natural token row (b*256 + i*16 + j)
__device__ __forceinline__ int natrow(int R) {
    int b = R >> 8, r8 = R & 255, w = r8 >> 2, t = r8 & 3;
    return (b << 8) + ((((w >> 3) << 1) + (t >> 1)) << 4) + ((w & 7) << 1) + (t & 1);
}

__device__ __forceinline__ void gll16(const void* g, void* l) {
    __builtin_amdgcn_global_load_lds(
        (const __attribute__((address_space(1))) void*)g,
        (__attribute__((address_space(3))) void*)l, 16, 0, 0);
}

// ---------- weight repack: [R][C] f32 -> [C][R] bf16 ----------
__device__ __forceinline__ void transpose_body(
    const float* __restrict__ in, u16* __restrict__ out, int R, int C)
{
    __shared__ float tile[32][33];
    const int tx = threadIdx.x, ty = threadIdx.y;
    const int c  = blockIdx.x * 32 + tx;
    const int r0 = blockIdx.y * 32;
#pragma unroll
    for (int i = 0; i < 32; i += 8) tile[ty + i][tx] = in[(size_t)(r0 + ty + i) * C + c];
    __syncthreads();
    const int orow0 = blockIdx.x * 32;
    const int ocol  = r0 + tx;
#pragma unroll
    for (int i = 0; i < 32; i += 8)
        out[(size_t)(orow0 + ty + i) * R + ocol] = f2b(tile[tx][ty + i]);
}

// z in [0,48): Wq heads 0-15, Wk 16-31, Wv 32-47; each head [1024][64] -> [64][1024]
__global__ __launch_bounds__(256) void transpose_qkv(
    const float* __restrict__ Wq, const float* __restrict__ Wk,
    const float* __restrict__ Wv, u16* __restrict__ out)
{
    const int z = blockIdx.z;
    const float* in = (z < 16 ? Wq : z < 32 ? Wk : Wv) + (size_t)(z & 15) * 65536;
    transpose_body(in, out + (size_t)z * 65536, 1024, 64);
}

// z in [0,3): Wp, W1, W2; [1024][1024] -> transposed, outputs contiguous
__global__ __launch_bounds__(256) void transpose_pw(
    const float* __restrict__ Wp, const float* __restrict__ W1,
    const float* __restrict__ W2, u16* __restrict__ out)
{
    const int z = blockIdx.z;
    const float* in = z == 0 ? Wp : z == 1 ? W1 : W2;
    transpose_body(in, out + (size_t)z * 1048576, 1024, 1024);
}

// ---------- LayerNorm; MAP = window-gather rows, BIN = bf16 input ----------
template<int MAP, int BIN>
__global__ __launch_bounds__(256) void ln_kernel(
    const void* __restrict__ X, const float* __restrict__ g, const float* __restrict__ bta,
    u16* __restrict__ outB)
{
    const int R   = blockIdx.x;
    const int src = MAP ? natrow(R) : R;
    float x0, x1, x2, x3;
    if (BIN) {
        const ushort4 r = ((const ushort4*)((const u16*)X + (size_t)src * 1024))[threadIdx.x];
        x0 = b2f(r.x); x1 = b2f(r.y); x2 = b2f(r.z); x3 = b2f(r.w);
    } else {
        const float4 r = ((const float4*)((const float*)X + (size_t)src * 1024))[threadIdx.x];
        x0 = r.x; x1 = r.y; x2 = r.z; x3 = r.w;
    }
    float s  = x0 + x1 + x2 + x3;
    float s2 = x0 * x0 + x1 * x1 + x2 * x2 + x3 * x3;
#pragma unroll
    for (int o = 32; o; o >>= 1) { s += __shfl_xor(s, o); s2 += __shfl_xor(s2, o); }
    __shared__ float red[8];
    const int w = threadIdx.x >> 6, l = threadIdx.x & 63;
    if (l == 0) { red[w] = s; red[w + 4] = s2; }
    __syncthreads();
    s  = red[0] + red[1] + red[2] + red[3];
    s2 = red[4] + red[5] + red[6] + red[7];
    const float mean = s * (1.f / 1024.f);
    const float var  = s2 * (1.f / 1024.f) - mean * mean;
    const float rinv = rsqrtf(var + 1e-5f);
    const float4 gv = ((const float4*)g)[threadIdx.x];
    const float4 bv = ((const float4*)bta)[threadIdx.x];
    ((ushort4*)(outB + (size_t)R * 1024))[threadIdx.x] = make_ushort4(
        f2b((x0 - mean) * rinv * gv.x + bv.x), f2b((x1 - mean) * rinv * gv.y + bv.y),
        f2b((x2 - mean) * rinv * gv.z + bv.z), f2b((x3 - mean) * rinv * gv.w + bv.w));
}

// ---------- 256x256 8-wave GEMM, BK=64, counted-vmcnt phases, L2 sub-chunks ----------
// C[M][N] = A[M][K](bf16, row stride LDA) @ Bt[N][K](bf16)^T
// MODE 0: bf16            MODE 2: gelu(+bias) -> bf16
// MODE 3: +bias + bf16 resid -> f32 at natrow     MODE 5: +bias + bf16 resid -> bf16
//
// Block order (NEW, r9): each XCD owns a contiguous stripe of R=C/NB mb-rows;
// within the stripe, blocks are ordered in 4x4 (mb,nb) sub-chunks so the
// staging working set per sub-chunk = 4 A-panels (2MB) + 4 B-panels (2MB)
// = 4MB = one XCD's L2. Cuts L3->L2 staging ~2.6x (B re-fetched ~2x not 8x).
// Requires nblk%8==0, NB%4==0, (nblk/8/NB)%4==0  (holds: 768/12, 256/4).
//
// LDS (128KB): A [d][half][128 rows][128B] at d*32K+half*16K; B at +64KB.
// Swizzle (3-bit): phys_byte = lin_byte ^ ((row&7)<<4); gll sources pre-permuted
// by same involution in 16B chunks: q = p ^ ((p>>3)&7).  (conflict-free, r3 PMC)
//
// Phase schedule per K-tile (snake quadrants, r8-verified):
//  ph0: vmcnt(4)+bar | ds a0,b0 (12) | stage A0(t+1) | lgkm0 | 16 MFMA
//  ph1: vmcnt(4)+bar | ds a1     (8) | stage B0(t+1) | lgkm0 | 16 MFMA
//  ph2: vmcnt(4)+bar | ds b1     (4) | stage A1(t+1) | lgkm0 | 16 MFMA
//  ph3:              |               | stage B1(t+1) |       | 16 MFMA
// Every awaited load >=3 phases old; counter never drains to 0 mid-loop.
template<int MODE>
__global__ __launch_bounds__(512, 2) void gemm256(
    const u16* __restrict__ A, const u16* __restrict__ Bt,
    const float* __restrict__ bias, const void* __restrict__ resid,
    void* __restrict__ Out, int M, int N, int K, int LDA, int NB)
{
    extern __shared__ char lds[];
    const int NT = K >> 6;
    const int nblk = gridDim.x;
    // --- 2D sub-chunked XCD ordering ---
    const int x = blockIdx.x & 7, i = blockIdx.x >> 3;
    const int R = (nblk >> 3) / NB;               // mb-rows per XCD stripe
    const int ncs = NB >> 2;                      // sub-chunk columns
    const int sc = i >> 4, u = i & 15;
    const int scr = sc / ncs, scc = sc - scr * ncs;
    const int mb = x * R + scr * 4 + (u >> 2);
    const int nb = scc * 4 + (u & 3);
    const int row0 = mb * 256, col0 = nb * 256;
    const int tid = threadIdx.x;
    const int w = tid >> 6, l = tid & 63;
    const int wr = w >> 2, wc = w & 3;
    const int lr = l & 15, kg = l >> 4;
    const int xs = (lr & 7) << 4;
    const int koff[2] = { (kg * 16) ^ xs, (64 + kg * 16) ^ xs };
    const int abase_l = wr * 8192 + lr * 128;
    const int bbase_l = wc * 4096 + lr * 128;

    f32x4 acc[2][2][4][2] = {};                   // [qm][qn][i][n]
    s16x8 a0[4][2], a1[4][2], b0[2][2], b1[2][2];

    auto stage = [&](int ts, int item) {          // item: 0=A0 1=B0 2=A1 3=B1
        if (ts >= NT) return;
        const int d = ts & 1;
        const int isB = item & 1, h = item >> 1;
        char* lbase = lds + (isB ? 65536 : 0) + d * 32768 + h * 16384;
        const u16* gptr = isB ? Bt : A;
        const int ld = isB ? K : LDA;
        const int blk0 = (isB ? col0 : row0) + h * 128;
#pragma unroll
        for (int j = 0; j < 2; ++j) {
            const int p = j * 512 + tid;
            const int q = p ^ ((p >> 3) & 7);     // involution, row-preserving
            const int grow = blk0 + (q >> 3);
            const int gcol = ts * 64 + (q & 7) * 8;
            gll16(gptr + (size_t)grow * ld + gcol, lbase + (j * 8 + w) * 1024);
        }
    };

#define SB __builtin_amdgcn_sched_barrier(0)
#define LOAD_A(dst, qm) do { \
    _Pragma("unroll") for (int kk = 0; kk < 2; ++kk) \
    _Pragma("unroll") for (int i2 = 0; i2 < 4; ++i2) \
        dst[i2][kk] = *(const s16x8*)(Ab + (qm) * 16384 + abase_l + i2 * 2048 + koff[kk]); \
} while (0)
#define LOAD_B(dst, qn) do { \
    _Pragma("unroll") for (int kk = 0; kk < 2; ++kk) \
    _Pragma("unroll") for (int n = 0; n < 2; ++n) \
        dst[n][kk] = *(const s16x8*)(Bb + (qn) * 16384 + bbase_l + n * 2048 + koff[kk]); \
} while (0)
#define LGKM0 do { \
    asm volatile("s_waitcnt lgkmcnt(0)" ::: "memory"); SB; \
} while (0)
#define MFMA_Q(qm, qn, aa, bb) do { \
    __builtin_amdgcn_s_setprio(1); \
    _Pragma("unroll") for (int kk = 0; kk < 2; ++kk) \
    _Pragma("unroll") for (int i2 = 0; i2 < 4; ++i2) \
    _Pragma("unroll") for (int n = 0; n < 2; ++n) \
        acc[qm][qn][i2][n] = __builtin_amdgcn_mfma_f32_16x16x32_bf16( \
            aa[i2][kk], bb[n][kk], acc[qm][qn][i2][n], 0, 0, 0); \
    __builtin_amdgcn_s_setprio(0); SB; \
} while (0)
#define GATE(NSTR) do { \
    asm volatile("s_waitcnt vmcnt(" NSTR ")" ::: "memory"); \
    __builtin_amdgcn_s_barrier(); SB; \
} while (0)

    // prologue: stage tile 0's four half-tiles (8 loads in flight)
    stage(0, 0); stage(0, 1); stage(0, 2); stage(0, 3);

    for (int t = 0; t < NT - 1; ++t) {
        const char* Ab = lds + (t & 1) * 32768;
        const char* Bb = lds + 65536 + (t & 1) * 32768;
        // ph0
        GATE("4");
        LOAD_A(a0, 0); LOAD_B(b0, 0); SB;
        stage(t + 1, 0); SB;
        LGKM0;
        MFMA_Q(0, 0, a0, b0);
        // ph1
        GATE("4");
        LOAD_A(a1, 1); SB;
        stage(t + 1, 1); SB;
        LGKM0;
        MFMA_Q(1, 0, a1, b0);
        // ph2
        GATE("4");
        LOAD_B(b1, 1); SB;
        stage(t + 1, 2); SB;
        LGKM0;
        MFMA_Q(1, 1, a1, b1);
        // ph3 (no wait, no barrier, no reads)
        stage(t + 1, 3); SB;
        MFMA_Q(0, 1, a0, b1);
    }
    {   // last tile, peeled: no stages; waits 4 / 2 / 0
        const int t = NT - 1;
        const char* Ab = lds + (t & 1) * 32768;
        const char* Bb = lds + 65536 + (t & 1) * 32768;
        GATE("4");
        LOAD_A(a0, 0); LOAD_B(b0, 0); SB;
        LGKM0;
        MFMA_Q(0, 0, a0, b0);
        GATE("2");
        LOAD_A(a1, 1); SB;
        LGKM0;
        MFMA_Q(1, 0, a1, b0);
        GATE("0");
        LOAD_B(b1, 1); SB;
        LGKM0;
        MFMA_Q(1, 1, a1, b1);
        MFMA_Q(0, 1, a0, b1);
    }
#undef SB
#undef LOAD_A
#undef LOAD_B
#undef LGKM0
#undef MFMA_Q
#undef GATE

    // epilogue
#pragma unroll
    for (int qm = 0; qm < 2; ++qm)
#pragma unroll
    for (int i2 = 0; i2 < 4; ++i2) {
        const int grb = row0 + qm * 128 + wr * 64 + i2 * 16 + kg * 4;
#pragma unroll
        for (int qn = 0; qn < 2; ++qn)
#pragma unroll
        for (int n = 0; n < 2; ++n) {
            const int gc = col0 + qn * 128 + wc * 32 + n * 16 + lr;
#pragma unroll
            for (int j = 0; j < 4; ++j) {
                const int gr = grb + j;
                const float v = acc[qm][qn][i2][n][j];
                if (MODE == 0) {
                    ((u16*)Out)[(size_t)gr * N + gc] = f2b(v);
                } else if (MODE == 2) {
                    const float tt = v + bias[gc];
                    ((u16*)Out)[(size_t)gr * N + gc] = f2b(0.5f * tt * (1.f + erff(tt * 0.70710678118f)));
                } else if (MODE == 3) {
                    ((float*)Out)[(size_t)natrow(gr) * N + gc] =
                        v + bias[gc] + b2f(((const u16*)resid)[(size_t)gr * N + gc]);
                } else {
                    ((u16*)Out)[(size_t)gr * N + gc] =
                        f2b(v + bias[gc] + b2f(((const u16*)resid)[(size_t)gr * N + gc]));
                }
            }
        }
    }
}

// ---------- tiny windowed attention, vectorized short8, in-place into q cols ----------
// one wave per window; lane l, chunk c covers cols c*512 + l*8 (head = c*8 + (l>>3))
__global__ __launch_bounds__(256) void attn_kernel(u16* __restrict__ QKV)
{
    const int w = threadIdx.x >> 6, l = threadIdx.x & 63;
    const int n = blockIdx.x * 4 + w;             // 4096 windows
    u16* base = QKV + (size_t)n * 4 * 3072;
    const float scale = 0.03125f;                 // C^-0.5 = 1/32 (d_model!)
#pragma unroll
    for (int c = 0; c < 2; ++c) {
        const int col = c * 512 + l * 8;
        u16x8 qr[4], kr[4], vr[4];
#pragma unroll
        for (int t = 0; t < 4; ++t) {
            qr[t] = *(const u16x8*)(base + t * 3072 + col);
            kr[t] = *(const u16x8*)(base + t * 3072 + 1024 + col);
            vr[t] = *(const u16x8*)(base + t * 3072 + 2048 + col);
        }
        float qf[4][8], kf[4][8];
#pragma unroll
        for (int t = 0; t < 4; ++t)
#pragma unroll
            for (int j = 0; j < 8; ++j) { qf[t][j] = b2f(qr[t][j]); kf[t][j] = b2f(kr[t][j]); }
        float s[4][4];
#pragma unroll
        for (int t = 0; t < 4; ++t)
#pragma unroll
            for (int u = 0; u < 4; ++u) {
                float p = qf[t][0] * kf[u][0];
#pragma unroll
                for (int j = 1; j < 8; ++j) p += qf[t][j] * kf[u][j];
                p += __shfl_xor(p, 1); p += __shfl_xor(p, 2); p += __shfl_xor(p, 4);
                s[t][u] = p * scale;              // per-head dot (8-lane group)
            }
#pragma unroll
        for (int t = 0; t < 4; ++t) {
            const float m = fmaxf(fmaxf(s[t][0], s[t][1]), fmaxf(s[t][2], s[t][3]));
            const float e0 = expf(s[t][0] - m), e1 = expf(s[t][1] - m);
            const float e2 = expf(s[t][2] - m), e3 = expf(s[t][3] - m);
            const float inv = 1.f / (e0 + e1 + e2 + e3);
            u16x8 o;
#pragma unroll
            for (int j = 0; j < 8; ++j)
                o[j] = f2b((e0 * b2f(vr[0][j]) + e1 * b2f(vr[1][j]) +
                            e2 * b2f(vr[2][j]) + e3 * b2f(vr[3][j])) * inv);
            *(u16x8*)(base + t * 3072 + col) = o; // overwrite own q slot (wave-private)
        }
    }
}

// ---------- launch ----------
extern "C" void kernel_launch(void* const* d_in, const int* in_sizes, int n_in,
                              void* d_out, int out_size, void* d_ws, size_t ws_size,
                              hipStream_t stream)
{
    const float* x    = (const float*)d_in[0];
    const float* ln1g = (const float*)d_in[1];
    const float* ln1b = (const float*)d_in[2];
    const float* Wq   = (const float*)d_in[3];
    const float* Wk   = (const float*)d_in[4];
    const float* Wv   = (const float*)d_in[5];
    const float* Wp   = (const float*)d_in[6];
    const float* bp   = (const float*)d_in[7];
    const float* ln2g = (const float*)d_in[8];
    const float* ln2b = (const float*)d_in[9];
    const float* W1   = (const float*)d_in[10];
    const float* b1   = (const float*)d_in[11];
    const float* W2   = (const float*)d_in[12];
    const float* b2   = (const float*)d_in[13];
    float* out = (float*)d_out;

    char* ws = (char*)d_ws;
    const size_t MB = 1024 * 1024;
    u16* xr_b  = (u16*)ws;                        // 32MB: xr bf16 (residual spine)
    u16* xw_b  = (u16*)(ws + 32 * MB);            // 32MB: ln1(x) windowed bf16
    u16* qkv   = (u16*)(ws + 64 * MB);            // 96MB: q|k|v; attn in-place; dead after proj
    u16* h1b   = (u16*)(ws + 64 * MB);            // 32MB: reuse of qkv region after proj
    u16* ln2bf = (u16*)(ws + 160 * MB);           // 32MB
    u16* WqkvT = (u16*)(ws + 192 * MB);           // 6MB [3072][1024]
    u16* WpT   = (u16*)(ws + 198 * MB);           // 3 x 2MB contiguous
    u16* W1T   = WpT + (1u << 20);
    u16* W2T   = W1T + (1u << 20);

    hipFuncSetAttribute((const void*)gemm256<0>, hipFuncAttributeMaxDynamicSharedMemorySize, 131072);
    hipFuncSetAttribute((const void*)gemm256<2>, hipFuncAttributeMaxDynamicSharedMemorySize, 131072);
    hipFuncSetAttribute((const void*)gemm256<3>, hipFuncAttributeMaxDynamicSharedMemorySize, 131072);
    hipFuncSetAttribute((const void*)gemm256<5>, hipFuncAttributeMaxDynamicSharedMemorySize, 131072);

    const int M = 16384, K = 1024;
    dim3 tpb(32, 8);
    transpose_qkv<<<dim3(2, 32, 48), tpb, 0, stream>>>(Wq, Wk, Wv, WqkvT);
    transpose_pw <<<dim3(32, 32, 3), tpb, 0, stream>>>(Wp, W1, W2, WpT);

    ln_kernel<1, 0><<<16384, 256, 0, stream>>>(x, ln1g, ln1b, xw_b);

    // qkv = xw @ [Wq|Wk|Wv]   (N=3072)
    gemm256<0><<<768, 512, 131072, stream>>>(xw_b, WqkvT, nullptr, nullptr, qkv, M, 3072, K, K, 12);

    attn_kernel<<<1024, 256, 0, stream>>>(qkv);    // att overwrites q columns

    // xr = att @ Wp + bp + xw  -> bf16 spine
    gemm256<5><<<256, 512, 131072, stream>>>(qkv, WpT, bp, xw_b, xr_b, M, 1024, K, 3072, 4);

    ln_kernel<0, 1><<<16384, 256, 0, stream>>>(xr_b, ln2g, ln2b, ln2bf);

    // h1 = gelu(ln2 @ W1 + b1)
    gemm256<2><<<256, 512, 131072, stream>>>(ln2bf, W1T, b1, nullptr, h1b, M, 1024, K, K, 4);

    // out[natrow] = h1 @ W2 + b2 + xr
    gemm256<3><<<256, 512, 131072, stream>>>(h1b, W2T, b2, xr_b, out, M, 1024, K, K, 4);
}